// Round 10
// baseline (804.896 us; speedup 1.0000x reference)
//
#include <hip/hip_runtime.h>
#include <hip/hip_bf16.h>

#define NUM_C 1024
#define EMB   512
#define HID   512
#define BATCH 64
#define SEQ   512

typedef short bf16x8 __attribute__((ext_vector_type(8)));
typedef float f32x4  __attribute__((ext_vector_type(4)));

__device__ __forceinline__ unsigned short f2bf(float x) {
    unsigned u = __float_as_uint(x);
    u += 0x7fffu + ((u >> 16) & 1u);
    return (unsigned short)(u >> 16);
}
__device__ __forceinline__ unsigned pack2bf(float a, float b) {
    return (unsigned)f2bf(a) | ((unsigned)f2bf(b) << 16);
}
__device__ __forceinline__ float uaf(unsigned u) { return __uint_as_float(u); }

// fast tanh: exact at +-inf, ~1e-7 rel err, no branches
__device__ __forceinline__ float ftanh(float x) {
    float e = __expf(2.f * x);
    return 1.f - 2.f / (e + 1.f);
}

// ---------------------------------------------------------------------------
__global__ __launch_bounds__(256) void f32_to_bf16(const float* __restrict__ src,
                                                   unsigned short* __restrict__ dst, int n) {
    int i = blockIdx.x * 256 + threadIdx.x;
    if (i < n) dst[i] = f2bf(src[i]);
}

// ---------------------------------------------------------------------------
// fp32 vector GEMM (NT) for emb_proj = emb @ Wx^T + Wx_b + Wh_b
// ---------------------------------------------------------------------------
__global__ __launch_bounds__(256)
void gemm_nt_f32(const float* __restrict__ A, const float* __restrict__ B,
                 float* __restrict__ C, int M, int N, int K,
                 const float* __restrict__ bias1, const float* __restrict__ bias2) {
    __shared__ float As[64][33];
    __shared__ float Bs[64][33];

    const int n0 = blockIdx.x * 64;
    const int m0 = blockIdx.y * 64;
    const int tid = threadIdx.x;
    const int tx = tid & 15;
    const int ty = tid >> 4;

    float acc[4][4] = {{0.f}};

    for (int k0 = 0; k0 < K; k0 += 32) {
        #pragma unroll
        for (int i = 0; i < 2; ++i) {
            int f   = tid * 2 + i;
            int row = f >> 3;
            int kf  = f & 7;
            float4 va = *(const float4*)&A[(size_t)(m0 + row) * K + k0 + kf * 4];
            float4 vb = *(const float4*)&B[(size_t)(n0 + row) * K + k0 + kf * 4];
            As[row][kf * 4 + 0] = va.x; As[row][kf * 4 + 1] = va.y;
            As[row][kf * 4 + 2] = va.z; As[row][kf * 4 + 3] = va.w;
            Bs[row][kf * 4 + 0] = vb.x; Bs[row][kf * 4 + 1] = vb.y;
            Bs[row][kf * 4 + 2] = vb.z; Bs[row][kf * 4 + 3] = vb.w;
        }
        __syncthreads();
        #pragma unroll
        for (int kk = 0; kk < 32; ++kk) {
            float a[4], b[4];
            #pragma unroll
            for (int i = 0; i < 4; ++i) a[i] = As[ty * 4 + i][kk];
            #pragma unroll
            for (int j = 0; j < 4; ++j) b[j] = Bs[tx * 4 + j][kk];
            #pragma unroll
            for (int i = 0; i < 4; ++i)
                #pragma unroll
                for (int j = 0; j < 4; ++j)
                    acc[i][j] += a[i] * b[j];
        }
        __syncthreads();
    }

    float bb[4];
    #pragma unroll
    for (int j = 0; j < 4; ++j) {
        int n = n0 + tx * 4 + j;
        bb[j] = bias1[n] + bias2[n];
    }
    #pragma unroll
    for (int i = 0; i < 4; ++i) {
        size_t m = (size_t)(m0 + ty * 4 + i);
        float4 ov;
        ov.x = acc[i][0] + bb[0]; ov.y = acc[i][1] + bb[1];
        ov.z = acc[i][2] + bb[2]; ov.w = acc[i][3] + bb[3];
        *(float4*)&C[m * N + n0 + tx * 4] = ov;
    }
}

// ---------------------------------------------------------------------------
// LTC scan v10 == v9 with launch_bounds(512,2): one block per (slice,batch),
// free-running, 1 barrier/step.  grid = 512 (sl = bid>>6, b = bid&63),
// 512 threads.  The ONLY change vs v9: VGPR cap 256 (was 128), so the
// 64-float W chunk stays RESIDENT in registers (v9's (512,4) forced the
// compiler to stream W from L2 every step -> VGPR 44, FETCH 98MB, L2-bound).
//   step s:  BAR | wave0: reduce ps + tanh -> h(s), store f32 to hx[s]
//                | all waves: poll hx[s] own 64-word k-chunk (f32, sentinel
//                  = NaN-exponent), readlane-broadcast mac -> ps_next
// h exchanged in f32 (|h|<1 => exp<=126; memset 0xFF = exp 255 sentinel);
// no pack/unpack on the critical path; recurrence exact f32.  hx doubles as
// the A operand of the output GEMM (bf16-converted during GEMM staging).
// ---------------------------------------------------------------------------
#define STEP9(PS_CUR, PS_NXT, S)                                               \
    __syncthreads();                                                           \
    if (fin) {                                                                 \
        float pre = e;                                                         \
        _Pragma("unroll")                                                      \
        for (int m = 0; m < 8; ++m) pre += PS_CUR[m * 64 + lane];              \
        float hn = h + (ftanh(pre) - h) * rtau;                                \
        h = hn;                                                                \
        __hip_atomic_store((unsigned*)&hxb[(S) * 512 + sl * 64 + lane],        \
                           __float_as_uint(hn), __ATOMIC_RELAXED,              \
                           __HIP_MEMORY_SCOPE_AGENT);                          \
        if ((S) + 1 < SEQ)                                                     \
            e = emb_proj[(size_t)ids[(S) + 1] * HID + sl * 64 + lane];         \
    }                                                                          \
    if ((S) + 1 < SEQ) {                                                       \
        unsigned* ap = (unsigned*)&hxb[(S) * 512 + w * 64 + lane];             \
        int wi = (int)__hip_atomic_load(ap, __ATOMIC_RELAXED,                  \
                                        __HIP_MEMORY_SCOPE_AGENT);             \
        while (((unsigned)wi & 0x7f800000u) == 0x7f800000u) {                  \
            __builtin_amdgcn_s_sleep(1);                                       \
            wi = (int)__hip_atomic_load(ap, __ATOMIC_RELAXED,                  \
                                        __HIP_MEMORY_SCOPE_AGENT);             \
        }                                                                      \
        float a0 = 0.f, a1 = 0.f, a2 = 0.f, a3 = 0.f;                          \
        _Pragma("unroll")                                                      \
        for (int t = 0; t < 64; t += 4) {                                      \
            a0 = fmaf(wf[t + 0],                                               \
                      uaf((unsigned)__builtin_amdgcn_readlane(wi, t + 0)), a0);\
            a1 = fmaf(wf[t + 1],                                               \
                      uaf((unsigned)__builtin_amdgcn_readlane(wi, t + 1)), a1);\
            a2 = fmaf(wf[t + 2],                                               \
                      uaf((unsigned)__builtin_amdgcn_readlane(wi, t + 2)), a2);\
            a3 = fmaf(wf[t + 3],                                               \
                      uaf((unsigned)__builtin_amdgcn_readlane(wi, t + 3)), a3);\
        }                                                                      \
        PS_NXT[w * 64 + lane] = (a0 + a1) + (a2 + a3);                         \
    }

__global__ __launch_bounds__(512, 2)
void ltc_scan10(const int* __restrict__ q, const int* __restrict__ r,
                const float* __restrict__ emb_proj, const float* __restrict__ Wh,
                const float* __restrict__ tau, float* __restrict__ hx) {
    __shared__ float psA[512], psB[512];
    __shared__ int   ids[512];

    const int tid  = threadIdx.x;
    const int sl   = blockIdx.x >> 6;     // slice: owns h rows sl*64..+63
    const int b    = blockIdx.x & 63;     // batch
    const int lane = tid & 63;
    const int w    = tid >> 6;            // wave = k-chunk = source slice

    // W chunk -> regs: row sl*64+lane, cols w*64..+63 (fp32, 64 VGPR)
    float wf[64];
    {
        const float* wrow = Wh + (size_t)(sl * 64 + lane) * 512 + w * 64;
        #pragma unroll
        for (int i = 0; i < 16; ++i) {
            float4 v = ((const float4*)wrow)[i];
            wf[4 * i + 0] = v.x; wf[4 * i + 1] = v.y;
            wf[4 * i + 2] = v.z; wf[4 * i + 3] = v.w;
        }
    }

    ids[tid] = q[b * SEQ + tid] + NUM_C * r[b * SEQ + tid];
    psA[tid] = 0.f;                        // partials for step 0 (h(-1)=0)

    const bool fin = (w == 0);             // wave 0 finishes all 64 rows
    float rtau = 0.f, h = 0.f, e = 0.f;
    if (fin) rtau = 1.0f / tau[sl * 64 + lane];

    float* hxb = hx + (size_t)b * SEQ * HID;
    __syncthreads();                       // ids, psA ready

    if (fin) e = emb_proj[(size_t)ids[0] * HID + sl * 64 + lane];

    for (int s = 0; s < SEQ; s += 2) {
        STEP9(psA, psB, s);
        STEP9(psB, psA, s + 1);
    }
}

// ---------------------------------------------------------------------------
// Output GEMM: y = sigmoid(A_f32 @ Wo_bf^T + Wo_b), bf16 MFMA 16x16x32.
// A is read in f32 (the scan's hx buffer) and converted to bf16 during LDS
// staging; B (Wo) is pre-converted bf16.
// ---------------------------------------------------------------------------
__global__ __launch_bounds__(256)
void gemm_out_bf16(const float* __restrict__ A,             // [M][512] f32
                   const unsigned short* __restrict__ B,    // [1024][512] bf16
                   const float* __restrict__ bias,
                   float* __restrict__ C, int M) {
    __shared__ __align__(16) unsigned short As[128 * 32];
    __shared__ __align__(16) unsigned short Bs[128 * 32];

    const int tid = threadIdx.x;
    const int n0 = blockIdx.x * 128;
    const int m0 = blockIdx.y * 128;
    const int w  = tid >> 6;
    const int l  = tid & 63;
    const int wr = w >> 1, wc = w & 1;
    const int lr = l & 15;
    const int lq = l >> 4;

    f32x4 acc[4][4];
    #pragma unroll
    for (int i = 0; i < 4; ++i)
        #pragma unroll
        for (int jn = 0; jn < 4; ++jn)
            acc[i][jn] = (f32x4){0.f, 0.f, 0.f, 0.f};

    for (int k0 = 0; k0 < 512; k0 += 32) {
        #pragma unroll
        for (int p = 0; p < 2; ++p) {
            int flat = p * 256 + tid;
            int row  = flat >> 2;
            int c4   = flat & 3;
            const float* asrc = &A[(size_t)(m0 + row) * 512 + k0 + c4 * 8];
            float4 v0 = ((const float4*)asrc)[0];
            float4 v1 = ((const float4*)asrc)[1];
            uint4 d;
            d.x = pack2bf(v0.x, v0.y); d.y = pack2bf(v0.z, v0.w);
            d.z = pack2bf(v1.x, v1.y); d.w = pack2bf(v1.z, v1.w);
            *(uint4*)&As[row * 32 + c4 * 8] = d;
            *(uint4*)&Bs[row * 32 + c4 * 8] =
                *(const uint4*)&B[(size_t)(n0 + row) * 512 + k0 + c4 * 8];
        }
        __syncthreads();

        bf16x8 af[4], bf[4];
        #pragma unroll
        for (int mf = 0; mf < 4; ++mf)
            af[mf] = *(const bf16x8*)&As[(wr * 64 + mf * 16 + lr) * 32 + lq * 8];
        #pragma unroll
        for (int nf = 0; nf < 4; ++nf)
            bf[nf] = *(const bf16x8*)&Bs[(wc * 64 + nf * 16 + lr) * 32 + lq * 8];

        #pragma unroll
        for (int mf = 0; mf < 4; ++mf)
            #pragma unroll
            for (int nf = 0; nf < 4; ++nf)
                acc[mf][nf] = __builtin_amdgcn_mfma_f32_16x16x32_bf16(
                    af[mf], bf[nf], acc[mf][nf], 0, 0, 0);
        __syncthreads();
    }

    #pragma unroll
    for (int mf = 0; mf < 4; ++mf) {
        #pragma unroll
        for (int nf = 0; nf < 4; ++nf) {
            int col = n0 + wc * 64 + nf * 16 + lr;
            float bb = bias[col];
            #pragma unroll
            for (int reg = 0; reg < 4; ++reg) {
                int rowm = m0 + wr * 64 + mf * 16 + lq * 4 + reg;
                float v = acc[mf][nf][reg] + bb;
                C[(size_t)rowm * 1024 + col] = 1.0f / (1.0f + expf(-v));
            }
        }
    }
}

// ---------------------------------------------------------------------------
extern "C" void kernel_launch(void* const* d_in, const int* in_sizes, int n_in,
                              void* d_out, int out_size, void* d_ws, size_t ws_size,
                              hipStream_t stream) {
    const int*   q    = (const int*)d_in[0];
    const int*   r    = (const int*)d_in[1];
    const float* emb  = (const float*)d_in[2];
    const float* Wh_w = (const float*)d_in[3];
    const float* Wh_b = (const float*)d_in[4];
    const float* Wx_w = (const float*)d_in[5];
    const float* Wx_b = (const float*)d_in[6];
    const float* tau  = (const float*)d_in[7];
    const float* Wo_w = (const float*)d_in[8];
    const float* Wo_b = (const float*)d_in[9];
    float* out = (float*)d_out;

    char* ws = (char*)d_ws;
    float*          emb_proj = (float*)ws;                           // 4 MiB
    unsigned short* Wobf     = (unsigned short*)(ws + (4u << 20));   // 1 MiB
    float*          hx       = (float*)(ws + (5u << 20));            // 64 MiB f32

    // sentinel-fill hx: 0xFF bytes -> exponent 255 (NaN); legit |h|<1 has
    // exponent <= 126, so any stored h clears the sentinel test.
    hipMemsetAsync(hx, 0xFF, (size_t)BATCH * SEQ * HID * 4, stream);

    // Wo -> bf16 for the MFMA output GEMM
    f32_to_bf16<<<(1024 * 512) / 256, 256, 0, stream>>>(Wo_w, Wobf, 1024 * 512);

    // emb_proj = emb @ Wx^T + Wx_b + Wh_b (2048 distinct interaction rows)
    gemm_nt_f32<<<dim3(512 / 64, 2048 / 64), 256, 0, stream>>>(
        emb, Wx_w, emb_proj, 2048, 512, 512, Wx_b, Wh_b);

    // recurrence: 512 blocks (8 slices x 64 batches), W resident in regs
    ltc_scan10<<<512, 512, 0, stream>>>(q, r, emb_proj, Wh_w, tau, hx);

    // y = sigmoid(hx @ Wo^T + Wo_b) via bf16 MFMA (A staged f32 -> bf16)
    gemm_out_bf16<<<dim3(1024 / 128, (BATCH * SEQ) / 128), 256, 0, stream>>>(
        hx, Wobf, Wo_b, out, BATCH * SEQ);
}